// Round 14
// baseline (330.083 us; speedup 1.0000x reference)
//
#include <hip/hip_runtime.h>
#include <hip/hip_bf16.h>
#include <math.h>

#define FFT_N 8192
#define HWN 196
#define CCH 2048
#define BATCH 16
#define PBLK 14   // blocks per batch
#define PPER 14   // positions per block (processed 2 at a time)
#define NPAIR 7

#define ZPAD(i) ((i) + ((i) >> 4))     // pad 1 float2 every 16 -> breaks pow2-stride conflicts
#define ZSZ 8704                        // 8192 + 512 pad

// position j (digit-reversed storage after DIF radix-4 x6 + radix-2) -> frequency k
__device__ __forceinline__ int kof(int j) {
    return ((j >> 11) & 3) | (((j >> 9) & 3) << 2) | (((j >> 7) & 3) << 4) |
           (((j >> 5) & 3) << 6) | (((j >> 3) & 3) << 8) | (((j >> 1) & 3) << 10) |
           ((j & 1) << 12);
}
// frequency k -> position j
__device__ __forceinline__ int pof(int k) {
    return ((k & 3) << 11) | (((k >> 2) & 3) << 9) | (((k >> 4) & 3) << 7) |
           (((k >> 6) & 3) << 5) | (((k >> 8) & 3) << 3) | (((k >> 10) & 3) << 1) |
           ((k >> 12) & 1);
}

// per-pass twiddle tables, stride-1 indexed by o: T[OFF+o] = exp(-2*pi*i*o*tstep/N)
// pass1 (tstep=1) stores only o<1024; o>=1024 multiplies by e^{-i*pi/4}.
// layout: 1024 @0, 512 @1024, 128 @1536, 32 @1664, 8 @1696, 2 @1704; total 1706
#define TW_TOTAL 1706

__device__ __forceinline__ float2 cmul(float2 a, float2 b) {
    return make_float2(a.x * b.x - a.y * b.y, a.x * b.y + a.y * b.x);
}

__device__ __forceinline__ void bf4(float2* z, int i0, int i1, int i2, int i3,
                                    float2 w1, float2 w2, float2 w3) {
    float2 a = z[i0], b = z[i1], c = z[i2], d = z[i3];
    float t0r = a.x + c.x, t0i = a.y + c.y, t1r = a.x - c.x, t1i = a.y - c.y;
    float t2r = b.x + d.x, t2i = b.y + d.y, t3r = b.x - d.x, t3i = b.y - d.y;
    float2 u0 = make_float2(t0r + t2r, t0i + t2i);
    float2 u2 = make_float2(t0r - t2r, t0i - t2i);
    float2 u1 = make_float2(t1r + t3i, t1i - t3r);  // t1 - i*t3
    float2 u3 = make_float2(t1r - t3i, t1i + t3r);  // t1 + i*t3
    z[i0] = u0;
    z[i1] = cmul(u1, w1);
    z[i2] = cmul(u2, w2);
    z[i3] = cmul(u3, w3);
}

template <int Q4, int OFF, bool DUAL>
__device__ __forceinline__ void pass4(float2* z0, float2* z1, const float2* T, int tid) {
#pragma unroll
    for (int it = 0; it < 2; ++it) {
        int u = tid + 1024 * it;
        int o = u & (Q4 - 1);
        int base = ((u & ~(Q4 - 1)) << 2) | o;
        int i0 = ZPAD(base), i1 = ZPAD(base + Q4);
        int i2 = ZPAD(base + 2 * Q4), i3 = ZPAD(base + 3 * Q4);
        float2 w1;
        if constexpr (Q4 == 2048) {
            w1 = T[o & 1023];
            if (o & 1024) {  // * e^{-i*pi/4}
                const float r = 0.70710678118654752f;
                w1 = make_float2(r * (w1.x + w1.y), r * (w1.y - w1.x));
            }
        } else {
            w1 = T[OFF + o];
        }
        float2 w2 = make_float2(w1.x * w1.x - w1.y * w1.y, 2.f * w1.x * w1.y);
        float2 w3 = cmul(w1, w2);
        bf4(z0, i0, i1, i2, i3, w1, w2, w3);
        if constexpr (DUAL) bf4(z1, i0, i1, i2, i3, w1, w2, w3);
    }
    __syncthreads();
}

// in-place DIF FFT (padded layout), natural input -> digit-reversed output (kof order)
template <bool DUAL>
__device__ __forceinline__ void fft8192d(float2* z0, float2* z1, const float2* T, int tid) {
    pass4<2048, 0, DUAL>(z0, z1, T, tid);
    pass4<512, 1024, DUAL>(z0, z1, T, tid);
    pass4<128, 1536, DUAL>(z0, z1, T, tid);
    pass4<32, 1664, DUAL>(z0, z1, T, tid);
    pass4<8, 1696, DUAL>(z0, z1, T, tid);
    pass4<2, 1704, DUAL>(z0, z1, T, tid);
    // final radix-2 pass on adjacent pairs
#pragma unroll
    for (int it = 0; it < 4; ++it) {
        int u = tid + 1024 * it;
        int i0 = ZPAD(2 * u), i1 = ZPAD(2 * u + 1);
        float2 a = z0[i0], b = z0[i1];
        z0[i0] = make_float2(a.x + b.x, a.y + b.y);
        z0[i1] = make_float2(a.x - b.x, a.y - b.y);
        if constexpr (DUAL) {
            float2 c = z1[i0], d = z1[i1];
            z1[i0] = make_float2(c.x + d.x, c.y + d.y);
            z1[i1] = make_float2(c.x - d.x, c.y - d.y);
        }
    }
    __syncthreads();
}

__device__ __forceinline__ void build_tables(float2* T, int tid) {
    const float w0 = -7.66990393942820573e-4f;  // -2*pi/8192
    {  // tstep 1, o < 1024
        float s, c; sincosf(w0 * (float)tid, &s, &c); T[tid] = make_float2(c, s);
    }
    if (tid < 512) {  // tstep 4
        float s, c; sincosf(w0 * (float)(tid * 4), &s, &c); T[1024 + tid] = make_float2(c, s);
    }
    if (tid < 128) {  // tstep 16
        float s, c; sincosf(w0 * (float)(tid * 16), &s, &c); T[1536 + tid] = make_float2(c, s);
    }
    if (tid < 32) {   // tstep 64
        float s, c; sincosf(w0 * (float)(tid * 64), &s, &c); T[1664 + tid] = make_float2(c, s);
    }
    if (tid < 8) {    // tstep 256
        float s, c; sincosf(w0 * (float)(tid * 256), &s, &c); T[1696 + tid] = make_float2(c, s);
    }
    if (tid < 2) {    // tstep 1024
        float s, c; sincosf(w0 * (float)(tid * 1024), &s, &c); T[1704 + tid] = make_float2(c, s);
    }
}

__global__ __launch_bounds__(1024) void cbp_fwd(
    const float* __restrict__ x, const int* __restrict__ h1,
    const int* __restrict__ h2, const int* __restrict__ s1,
    const int* __restrict__ s2, float2* __restrict__ acc) {
    __shared__ float2 zs[2][ZSZ];
    __shared__ float2 T[TW_TOTAL];
    int tid = threadIdx.x;
    int b = blockIdx.x / PBLK;
    int pb = blockIdx.x % PBLK;

    int c0 = tid, c1 = tid + 1024;

    // ---- read ALL of this block's x data ONCE into registers (28 VGPRs) ----
    const float2* pA = (const float2*)(x + ((size_t)b * CCH + c0) * HWN + pb * PPER);
    const float2* pB = (const float2*)(x + ((size_t)b * CCH + c1) * HWN + pb * PPER);
    float2 xA[NPAIR], xB[NPAIR];
#pragma unroll
    for (int q = 0; q < NPAIR; ++q) xA[q] = pA[q];
#pragma unroll
    for (int q = 0; q < NPAIR; ++q) xB[q] = pB[q];

    build_tables(T, tid);

    int h1a = ZPAD(h1[c0]), h2a = ZPAD(h2[c0]);
    int h1b = ZPAD(h1[c1]), h2b = ZPAD(h2[c1]);
    float g1a = (float)(2 * s1[c0] - 1), g2a = (float)(2 * s2[c0] - 1);
    float g1b = (float)(2 * s1[c1] - 1), g2b = (float)(2 * s2[c1] - 1);

    float accR[8], accI[8];
#pragma unroll
    for (int s = 0; s < 8; s++) { accR[s] = 0.f; accI[s] = 0.f; }

    float2* z0 = zs[0];
    float2* z1 = zs[1];
    float2* zf2 = (float2*)zs;

#pragma unroll
    for (int ii = 0; ii < NPAIR; ++ii) {
        float2 va = xA[ii];   // (.x = pos 2*ii, .y = pos 2*ii+1), channel c0
        float2 vb = xB[ii];   // same, channel c1

        // zero both padded buffers (2*ZSZ float2 = 17408 = 17*1024)
#pragma unroll
        for (int i = 0; i < 17; ++i) zf2[tid + 1024 * i] = make_float2(0.f, 0.f);
        __syncthreads();

        atomicAdd(&z0[h1a].x, g1a * va.x);
        atomicAdd(&z0[h2a].y, g2a * va.x);
        atomicAdd(&z0[h1b].x, g1b * vb.x);
        atomicAdd(&z0[h2b].y, g2b * vb.x);
        atomicAdd(&z1[h1a].x, g1a * va.y);
        atomicAdd(&z1[h2a].y, g2a * va.y);
        atomicAdd(&z1[h1b].x, g1b * vb.y);
        atomicAdd(&z1[h2b].y, g2b * vb.y);
        __syncthreads();

        fft8192d<true>(z0, z1, T, tid);

        // P[k] = -i/4 * (Z[k]^2 - conj(Z[N-k])^2), accumulated per position j
#pragma unroll
        for (int s = 0; s < 8; s++) {
            int j = tid + 1024 * s;
            int k = kof(j);
            int m = (FFT_N - k) & (FFT_N - 1);
            int j2 = pof(m);
            int pj = ZPAD(j), pj2 = ZPAD(j2);
            float2 a0 = z0[pj], b0 = z0[pj2];
            float2 a1 = z1[pj], b1 = z1[pj2];
            float Dr = (a0.x * a0.x - a0.y * a0.y) - (b0.x * b0.x - b0.y * b0.y)
                     + (a1.x * a1.x - a1.y * a1.y) - (b1.x * b1.x - b1.y * b1.y);
            float Di = 2.f * (a0.x * a0.y + b0.x * b0.y)
                     + 2.f * (a1.x * a1.y + b1.x * b1.y);
            accR[s] += 0.25f * Di;
            accI[s] -= 0.25f * Dr;
        }
        __syncthreads();
    }

    float2* ab = acc + (size_t)b * FFT_N;
#pragma unroll
    for (int s = 0; s < 8; s++) {
        int j = tid + 1024 * s;
        atomicAdd(&ab[j].x, accR[s]);
        atomicAdd(&ab[j].y, accI[s]);
    }
}

__global__ __launch_bounds__(1024) void cbp_inv(
    const float2* __restrict__ acc, float* __restrict__ out) {
    __shared__ float2 z[ZSZ];
    __shared__ float2 T[TW_TOTAL];
    __shared__ float red[20];
    int tid = threadIdx.x;
    int b = blockIdx.x;

    build_tables(T, tid);

    const float2* ab = acc + (size_t)b * FFT_N;
    // IFFT(P) = conj(FFT(conj(P)))/N; load conj(P) in natural frequency order
#pragma unroll
    for (int s = 0; s < 8; s++) {
        int j = tid + 1024 * s;
        float2 v = ab[j];
        z[ZPAD(kof(j))] = make_float2(v.x, -v.y);
    }
    __syncthreads();

    fft8192d<false>(z, z, T, tid);

    float sv[8];
    float ss = 0.f;
#pragma unroll
    for (int s = 0; s < 8; s++) {
        int j = tid + 1024 * s;
        float v = z[ZPAD(j)].x * (1.f / (float)FFT_N);
        float r = copysignf(sqrtf(fabsf(v) + 1e-5f), v);
        sv[s] = r;
        ss += r * r;
    }
    // block reduction of ss
#pragma unroll
    for (int m = 32; m >= 1; m >>= 1) ss += __shfl_xor(ss, m);
    int wave = tid >> 6, lane = tid & 63;
    if (lane == 0) red[wave] = ss;
    __syncthreads();
    if (tid == 0) {
        float tot = 0.f;
        for (int w = 0; w < 16; w++) tot += red[w];
        red[16] = fmaxf(sqrtf(tot), 1e-12f);
    }
    __syncthreads();
    float inv = 1.f / red[16];
    float* ob = out + (size_t)b * FFT_N;
#pragma unroll
    for (int s = 0; s < 8; s++) {
        int j = tid + 1024 * s;
        ob[kof(j)] = sv[s] * inv;
    }
}

extern "C" void kernel_launch(void* const* d_in, const int* in_sizes, int n_in,
                              void* d_out, int out_size, void* d_ws, size_t ws_size,
                              hipStream_t stream) {
    const float* x = (const float*)d_in[0];
    const int* h1 = (const int*)d_in[1];
    const int* h2 = (const int*)d_in[2];
    const int* s1 = (const int*)d_in[3];
    const int* s2 = (const int*)d_in[4];
    float* out = (float*)d_out;
    float2* acc = (float2*)d_ws;

    hipMemsetAsync(acc, 0, (size_t)BATCH * FFT_N * sizeof(float2), stream);
    cbp_fwd<<<BATCH * PBLK, 1024, 0, stream>>>(x, h1, h2, s1, s2, acc);
    cbp_inv<<<BATCH, 1024, 0, stream>>>(acc, (float*)out);
}

// Round 15
// 283.369 us; speedup vs baseline: 1.1649x; 1.1649x over previous
//
#include <hip/hip_runtime.h>
#include <hip/hip_bf16.h>
#include <math.h>

#define FFT_N 8192
#define HWN 196
#define CCH 2048
#define BATCH 16
#define PBLK 14   // blocks per batch
#define PPER 14   // positions per block (processed 2 at a time)
#define NPAIR 7

#define ZPAD(i) ((i) + ((i) >> 4))     // pad 1 float2 every 16 -> breaks pow2-stride conflicts
#define ZSZ 8704                        // 8192 + 512 pad

// Radix-8 DIF x4 + radix-2. Digit written at stride q in pass p = k-digit of
// significance 8^(p-1); strides 1024,128,16,2 then radix-2 stride 1 -> k bit 12.
// position j (digit-reversed storage) -> frequency k
__device__ __forceinline__ int kof8(int j) {
    return ((j >> 10) & 7) | (((j >> 7) & 7) << 3) | (((j >> 4) & 7) << 6) |
           (((j >> 1) & 7) << 9) | ((j & 1) << 12);
}
// frequency k -> position j
__device__ __forceinline__ int pof8(int k) {
    return ((k & 7) << 10) | (((k >> 3) & 7) << 7) | (((k >> 6) & 7) << 4) |
           (((k >> 9) & 7) << 1) | ((k >> 12) & 1);
}

// twiddle tables, stride-1 by o: pass1 (tstep=1) 1024 @0; pass2 (tstep=8) 128 @1024;
// pass3 (tstep=64) 16 @1152; pass4 (tstep=512) 2 @1168. total 1170
#define TW_TOTAL 1170

__device__ __forceinline__ float2 cmul(float2 a, float2 b) {
    return make_float2(a.x * b.x - a.y * b.y, a.x * b.y + a.y * b.x);
}
__device__ __forceinline__ float2 cadd(float2 a, float2 b) { return make_float2(a.x + b.x, a.y + b.y); }
__device__ __forceinline__ float2 csub(float2 a, float2 b) { return make_float2(a.x - b.x, a.y - b.y); }

// radix-8 DIF butterfly at 8 padded indices, with external twiddles w1..w7
__device__ __forceinline__ void bf8(float2* z, int i0, int i1, int i2, int i3,
                                    int i4, int i5, int i6, int i7,
                                    float2 w1, float2 w2, float2 w3, float2 w4,
                                    float2 w5, float2 w6, float2 w7) {
    float2 a0 = z[i0], a1 = z[i1], a2 = z[i2], a3 = z[i3];
    float2 a4 = z[i4], a5 = z[i5], a6 = z[i6], a7 = z[i7];
    float2 b0 = cadd(a0, a4), b1 = cadd(a1, a5), b2 = cadd(a2, a6), b3 = cadd(a3, a7);
    float2 c0 = csub(a0, a4), c1 = csub(a1, a5), c2 = csub(a2, a6), c3 = csub(a3, a7);
    const float r = 0.70710678118654752f;
    // c1 *= W8 = (1-i)/sqrt2 ; c2 *= -i ; c3 *= W8^3 = (-1-i)/sqrt2
    c1 = make_float2(r * (c1.x + c1.y), r * (c1.y - c1.x));
    c2 = make_float2(c2.y, -c2.x);
    c3 = make_float2(r * (c3.y - c3.x), -r * (c3.x + c3.y));
    // FFT4(d): t0=d0+d2,t1=d0-d2,t2=d1+d3,t3=d1-d3; o0=t0+t2,o1=t1-i*t3,o2=t0-t2,o3=t1+i*t3
    float2 t0, t1, t2, t3;
    t0 = cadd(b0, b2); t1 = csub(b0, b2); t2 = cadd(b1, b3); t3 = csub(b1, b3);
    float2 E0 = cadd(t0, t2);
    float2 E1 = make_float2(t1.x + t3.y, t1.y - t3.x);
    float2 E2 = csub(t0, t2);
    float2 E3 = make_float2(t1.x - t3.y, t1.y + t3.x);
    t0 = cadd(c0, c2); t1 = csub(c0, c2); t2 = cadd(c1, c3); t3 = csub(c1, c3);
    float2 O0 = cadd(t0, t2);
    float2 O1 = make_float2(t1.x + t3.y, t1.y - t3.x);
    float2 O2 = csub(t0, t2);
    float2 O3 = make_float2(t1.x - t3.y, t1.y + t3.x);
    // out_s: even->E[s/2], odd->O[(s-1)/2]; store *w_s
    z[i0] = E0;
    z[i1] = cmul(O0, w1);
    z[i2] = cmul(E1, w2);
    z[i3] = cmul(O1, w3);
    z[i4] = cmul(E2, w4);
    z[i5] = cmul(O2, w5);
    z[i6] = cmul(E3, w6);
    z[i7] = cmul(O3, w7);
}

template <int Q, int TOFF, bool DUAL>
__device__ __forceinline__ void pass8(float2* z0, float2* z1, const float2* T, int tid) {
    int o = tid & (Q - 1);
    int base = ((tid & ~(Q - 1)) << 3) | o;
    int i0 = ZPAD(base), i1 = ZPAD(base + Q), i2 = ZPAD(base + 2 * Q), i3 = ZPAD(base + 3 * Q);
    int i4 = ZPAD(base + 4 * Q), i5 = ZPAD(base + 5 * Q), i6 = ZPAD(base + 6 * Q), i7 = ZPAD(base + 7 * Q);
    float2 w1 = T[TOFF + o];
    float2 w2 = cmul(w1, w1);
    float2 w3 = cmul(w2, w1);
    float2 w4 = cmul(w2, w2);
    float2 w5 = cmul(w2, w3);
    float2 w6 = cmul(w3, w3);
    float2 w7 = cmul(w3, w4);
    bf8(z0, i0, i1, i2, i3, i4, i5, i6, i7, w1, w2, w3, w4, w5, w6, w7);
    if constexpr (DUAL) bf8(z1, i0, i1, i2, i3, i4, i5, i6, i7, w1, w2, w3, w4, w5, w6, w7);
    __syncthreads();
}

// in-place DIF FFT (padded layout), natural input -> digit-reversed output (kof8 order)
template <bool DUAL>
__device__ __forceinline__ void fft8192d(float2* z0, float2* z1, const float2* T, int tid) {
    pass8<1024, 0, DUAL>(z0, z1, T, tid);
    pass8<128, 1024, DUAL>(z0, z1, T, tid);
    pass8<16, 1152, DUAL>(z0, z1, T, tid);
    pass8<2, 1168, DUAL>(z0, z1, T, tid);
    // final radix-2 pass on adjacent pairs
#pragma unroll
    for (int it = 0; it < 4; ++it) {
        int u = tid + 1024 * it;
        int i0 = ZPAD(2 * u), i1 = ZPAD(2 * u + 1);
        float2 a = z0[i0], b = z0[i1];
        z0[i0] = cadd(a, b);
        z0[i1] = csub(a, b);
        if constexpr (DUAL) {
            float2 c = z1[i0], d = z1[i1];
            z1[i0] = cadd(c, d);
            z1[i1] = csub(c, d);
        }
    }
    __syncthreads();
}

__device__ __forceinline__ void build_tables(float2* T, int tid) {
    const float w0 = -7.66990393942820573e-4f;  // -2*pi/8192
    {  // tstep 1
        float s, c; sincosf(w0 * (float)tid, &s, &c); T[tid] = make_float2(c, s);
    }
    if (tid < 128) {  // tstep 8
        float s, c; sincosf(w0 * (float)(tid * 8), &s, &c); T[1024 + tid] = make_float2(c, s);
    }
    if (tid < 16) {   // tstep 64
        float s, c; sincosf(w0 * (float)(tid * 64), &s, &c); T[1152 + tid] = make_float2(c, s);
    }
    if (tid < 2) {    // tstep 512
        float s, c; sincosf(w0 * (float)(tid * 512), &s, &c); T[1168 + tid] = make_float2(c, s);
    }
}

__global__ __launch_bounds__(1024, 4) void cbp_fwd(
    const float* __restrict__ x, const int* __restrict__ h1,
    const int* __restrict__ h2, const int* __restrict__ s1,
    const int* __restrict__ s2, float2* __restrict__ acc) {
    __shared__ float2 zs[2][ZSZ];
    __shared__ float2 T[TW_TOTAL];
    int tid = threadIdx.x;
    int b = blockIdx.x / PBLK;
    int pb = blockIdx.x % PBLK;

    int c0 = tid, c1 = tid + 1024;

    // ---- read ALL of this block's x data ONCE into registers (28 VGPRs) ----
    const float2* pA = (const float2*)(x + ((size_t)b * CCH + c0) * HWN + pb * PPER);
    const float2* pB = (const float2*)(x + ((size_t)b * CCH + c1) * HWN + pb * PPER);
    float2 xA[NPAIR], xB[NPAIR];
#pragma unroll
    for (int q = 0; q < NPAIR; ++q) xA[q] = pA[q];
#pragma unroll
    for (int q = 0; q < NPAIR; ++q) xB[q] = pB[q];

    build_tables(T, tid);

    int h1a = ZPAD(h1[c0]), h2a = ZPAD(h2[c0]);
    int h1b = ZPAD(h1[c1]), h2b = ZPAD(h2[c1]);
    float g1a = (float)(2 * s1[c0] - 1), g2a = (float)(2 * s2[c0] - 1);
    float g1b = (float)(2 * s1[c1] - 1), g2b = (float)(2 * s2[c1] - 1);

    float accR[8], accI[8];
#pragma unroll
    for (int s = 0; s < 8; s++) { accR[s] = 0.f; accI[s] = 0.f; }

    float2* z0 = zs[0];
    float2* z1 = zs[1];
    float2* zf2 = (float2*)zs;

#pragma unroll
    for (int ii = 0; ii < NPAIR; ++ii) {
        float2 va = xA[ii];   // (.x = pos 2*ii, .y = pos 2*ii+1), channel c0
        float2 vb = xB[ii];   // same, channel c1

        // zero both padded buffers (2*ZSZ float2 = 17408 = 17*1024)
#pragma unroll
        for (int i = 0; i < 17; ++i) zf2[tid + 1024 * i] = make_float2(0.f, 0.f);
        __syncthreads();

        atomicAdd(&z0[h1a].x, g1a * va.x);
        atomicAdd(&z0[h2a].y, g2a * va.x);
        atomicAdd(&z0[h1b].x, g1b * vb.x);
        atomicAdd(&z0[h2b].y, g2b * vb.x);
        atomicAdd(&z1[h1a].x, g1a * va.y);
        atomicAdd(&z1[h2a].y, g2a * va.y);
        atomicAdd(&z1[h1b].x, g1b * vb.y);
        atomicAdd(&z1[h2b].y, g2b * vb.y);
        __syncthreads();

        fft8192d<true>(z0, z1, T, tid);

        // P[k] = -i/4 * (Z[k]^2 - conj(Z[N-k])^2), accumulated per position j
#pragma unroll
        for (int s = 0; s < 8; s++) {
            int j = tid + 1024 * s;
            int k = kof8(j);
            int m = (FFT_N - k) & (FFT_N - 1);
            int j2 = pof8(m);
            int pj = ZPAD(j), pj2 = ZPAD(j2);
            float2 a0 = z0[pj], b0 = z0[pj2];
            float2 a1 = z1[pj], b1 = z1[pj2];
            float Dr = (a0.x * a0.x - a0.y * a0.y) - (b0.x * b0.x - b0.y * b0.y)
                     + (a1.x * a1.x - a1.y * a1.y) - (b1.x * b1.x - b1.y * b1.y);
            float Di = 2.f * (a0.x * a0.y + b0.x * b0.y)
                     + 2.f * (a1.x * a1.y + b1.x * b1.y);
            accR[s] += 0.25f * Di;
            accI[s] -= 0.25f * Dr;
        }
        __syncthreads();
    }

    float2* ab = acc + (size_t)b * FFT_N;
#pragma unroll
    for (int s = 0; s < 8; s++) {
        int j = tid + 1024 * s;
        atomicAdd(&ab[j].x, accR[s]);
        atomicAdd(&ab[j].y, accI[s]);
    }
}

__global__ __launch_bounds__(1024, 4) void cbp_inv(
    const float2* __restrict__ acc, float* __restrict__ out) {
    __shared__ float2 z[ZSZ];
    __shared__ float2 T[TW_TOTAL];
    __shared__ float red[20];
    int tid = threadIdx.x;
    int b = blockIdx.x;

    build_tables(T, tid);

    const float2* ab = acc + (size_t)b * FFT_N;
    // IFFT(P) = conj(FFT(conj(P)))/N; load conj(P) in natural frequency order
#pragma unroll
    for (int s = 0; s < 8; s++) {
        int j = tid + 1024 * s;
        float2 v = ab[j];
        z[ZPAD(kof8(j))] = make_float2(v.x, -v.y);
    }
    __syncthreads();

    fft8192d<false>(z, z, T, tid);

    float sv[8];
    float ss = 0.f;
#pragma unroll
    for (int s = 0; s < 8; s++) {
        int j = tid + 1024 * s;
        float v = z[ZPAD(j)].x * (1.f / (float)FFT_N);
        float r = copysignf(sqrtf(fabsf(v) + 1e-5f), v);
        sv[s] = r;
        ss += r * r;
    }
    // block reduction of ss
#pragma unroll
    for (int m = 32; m >= 1; m >>= 1) ss += __shfl_xor(ss, m);
    int wave = tid >> 6, lane = tid & 63;
    if (lane == 0) red[wave] = ss;
    __syncthreads();
    if (tid == 0) {
        float tot = 0.f;
        for (int w = 0; w < 16; w++) tot += red[w];
        red[16] = fmaxf(sqrtf(tot), 1e-12f);
    }
    __syncthreads();
    float inv = 1.f / red[16];
    float* ob = out + (size_t)b * FFT_N;
#pragma unroll
    for (int s = 0; s < 8; s++) {
        int j = tid + 1024 * s;
        ob[kof8(j)] = sv[s] * inv;
    }
}

extern "C" void kernel_launch(void* const* d_in, const int* in_sizes, int n_in,
                              void* d_out, int out_size, void* d_ws, size_t ws_size,
                              hipStream_t stream) {
    const float* x = (const float*)d_in[0];
    const int* h1 = (const int*)d_in[1];
    const int* h2 = (const int*)d_in[2];
    const int* s1 = (const int*)d_in[3];
    const int* s2 = (const int*)d_in[4];
    float* out = (float*)d_out;
    float2* acc = (float2*)d_ws;

    hipMemsetAsync(acc, 0, (size_t)BATCH * FFT_N * sizeof(float2), stream);
    cbp_fwd<<<BATCH * PBLK, 1024, 0, stream>>>(x, h1, h2, s1, s2, acc);
    cbp_inv<<<BATCH, 1024, 0, stream>>>(acc, (float*)out);
}